// Round 1
// baseline (359.134 us; speedup 1.0000x reference)
//
#include <hip/hip_runtime.h>
#include <hip/hip_bf16.h>
#include <cstdio>
#include <cstdint>

#define T_TOK 8192
#define H_DIM 2048
#define N_EXP 8
#define BM 128
#define BN 128
#define BK 32
#define MAX_TILES 72
#define LDS_STRIDE 36  // BK + 4 shorts pad -> 72B row stride, conflict-friendly

typedef __attribute__((ext_vector_type(4))) float f32x4;
typedef __attribute__((ext_vector_type(8))) short bf16x8;

__device__ __forceinline__ unsigned short f2bf(float f) {
  unsigned int u = __builtin_bit_cast(unsigned int, f);
  u += 0x7fffu + ((u >> 16) & 1u);  // RNE (inputs are finite)
  return (unsigned short)(u >> 16);
}

// ---- phase 1: router logits + argmax + bf16 cast of x ----
__global__ __launch_bounds__(256) void k_router(const float* __restrict__ x,
    const float* __restrict__ wr, unsigned short* __restrict__ xb,
    int* __restrict__ idx, int* __restrict__ counts)
{
  const int wv = threadIdx.x >> 6, lane = threadIdx.x & 63;
  const int t = blockIdx.x * 4 + wv;
  const float* xp = x + (size_t)t * H_DIM;
  float acc[N_EXP];
#pragma unroll
  for (int e = 0; e < N_EXP; ++e) acc[e] = 0.f;
#pragma unroll
  for (int c = 0; c < H_DIM / 256; ++c) {
    const int h = c * 256 + lane * 4;
    const float4 xv = *reinterpret_cast<const float4*>(xp + h);
    ushort4 bv;
    bv.x = f2bf(xv.x); bv.y = f2bf(xv.y); bv.z = f2bf(xv.z); bv.w = f2bf(xv.w);
    *reinterpret_cast<ushort4*>(xb + (size_t)t * H_DIM + h) = bv;
#pragma unroll
    for (int e = 0; e < N_EXP; ++e) {
      const float4 wv4 = *reinterpret_cast<const float4*>(wr + e * H_DIM + h);
      acc[e] = fmaf(xv.x, wv4.x, acc[e]);
      acc[e] = fmaf(xv.y, wv4.y, acc[e]);
      acc[e] = fmaf(xv.z, wv4.z, acc[e]);
      acc[e] = fmaf(xv.w, wv4.w, acc[e]);
    }
  }
#pragma unroll
  for (int off = 32; off >= 1; off >>= 1)
#pragma unroll
    for (int e = 0; e < N_EXP; ++e) acc[e] += __shfl_xor(acc[e], off, 64);
  float best = acc[0]; int be = 0;
#pragma unroll
  for (int e = 1; e < N_EXP; ++e) if (acc[e] > best) { best = acc[e]; be = e; }
  if (lane == 0) { idx[t] = be; atomicAdd(&counts[be], 1); }
}

__global__ void k_zero(int* counts) {
  if (threadIdx.x < N_EXP) counts[threadIdx.x] = 0;
}

// ---- phase 2: exclusive scan + tile map (trivial: E=8) ----
__global__ void k_scan(const int* __restrict__ counts, int* __restrict__ cursor,
                       int* __restrict__ te, int* __restrict__ tstart,
                       int* __restrict__ tcnt, int* __restrict__ ntiles)
{
  if (threadIdx.x != 0 || blockIdx.x != 0) return;
  int off = 0, n = 0;
  for (int e = 0; e < N_EXP; ++e) {
    cursor[e] = off;
    const int c = counts[e];
    for (int j = 0; j < c; j += BM) {
      te[n] = e; tstart[n] = off + j;
      tcnt[n] = (c - j < BM) ? (c - j) : BM;
      ++n;
    }
    off += c;
  }
  *ntiles = n;
}

__global__ __launch_bounds__(256) void k_scatter(const int* __restrict__ idx,
    int* __restrict__ cursor, int* __restrict__ tlist)
{
  const int t = blockIdx.x * 256 + threadIdx.x;
  const int e = idx[t];
  const int p = atomicAdd(&cursor[e], 1);
  tlist[p] = t;
}

// ---- phase 3: grouped GEMM  out[t,f] = sum_h xb[t,h] * W_e[f,h] ----
__global__ __launch_bounds__(256) void k_gemm(const unsigned short* __restrict__ xb,
    const float* __restrict__ we, const int* __restrict__ tlist,
    const int* __restrict__ te, const int* __restrict__ tstart,
    const int* __restrict__ tcnt, const int* __restrict__ ntiles,
    float* __restrict__ out)
{
  const int bt = blockIdx.x;
  if (bt >= *ntiles) return;
  const int e = te[bt], ts = tstart[bt], cnt = tcnt[bt];
  const int f0 = blockIdx.y * BN;

  __shared__ short As[BM][LDS_STRIDE];
  __shared__ short Bs[BN][LDS_STRIDE];

  const int tid = threadIdx.x;
  const int wv = tid >> 6, lane = tid & 63;
  const int wr = wv >> 1, wc = wv & 1;       // 2x2 wave grid, 64x64 each
  const int l16 = lane & 15, g = lane >> 4;

  int tok[4];
#pragma unroll
  for (int i = 0; i < 4; ++i) {
    const int row = (tid + i * 256) >> 3;
    tok[i] = tlist[ts + (row < cnt ? row : cnt - 1)];  // clamp; dup rows never stored
  }
  const float* wb = we + (size_t)e * H_DIM * H_DIM;

  f32x4 acc[4][4];
#pragma unroll
  for (int mi = 0; mi < 4; ++mi)
#pragma unroll
    for (int ni = 0; ni < 4; ++ni) acc[mi][ni] = (f32x4){0.f, 0.f, 0.f, 0.f};

  union Frag { short4 h[2]; bf16x8 v; };

  for (int k0 = 0; k0 < H_DIM; k0 += BK) {
    __syncthreads();
#pragma unroll
    for (int i = 0; i < 4; ++i) {
      const int u = tid + i * 256;
      const int row = u >> 3, c4 = (u & 7) * 4;
      // A: gathered bf16 token rows (8B per thread)
      *reinterpret_cast<short4*>(&As[row][c4]) =
          *reinterpret_cast<const short4*>(xb + (size_t)tok[i] * H_DIM + k0 + c4);
      // B: W_e rows, f32 -> bf16 on the fly
      const f32x4 wv4 = *reinterpret_cast<const f32x4*>(
          wb + (size_t)(f0 + row) * H_DIM + k0 + c4);
      short4 bv;
      bv.x = (short)f2bf(wv4.x); bv.y = (short)f2bf(wv4.y);
      bv.z = (short)f2bf(wv4.z); bv.w = (short)f2bf(wv4.w);
      *reinterpret_cast<short4*>(&Bs[row][c4]) = bv;
    }
    __syncthreads();

    bf16x8 af[4], bf[4];
#pragma unroll
    for (int mi = 0; mi < 4; ++mi) {
      Frag fr;
      const short* p = &As[wr * 64 + mi * 16 + l16][g * 4];
      fr.h[0] = *reinterpret_cast<const short4*>(p);
      fr.h[1] = *reinterpret_cast<const short4*>(p + 16);
      af[mi] = fr.v;
    }
#pragma unroll
    for (int ni = 0; ni < 4; ++ni) {
      Frag fr;
      const short* p = &Bs[wc * 64 + ni * 16 + l16][g * 4];
      fr.h[0] = *reinterpret_cast<const short4*>(p);
      fr.h[1] = *reinterpret_cast<const short4*>(p + 16);
      bf[ni] = fr.v;
    }
#pragma unroll
    for (int mi = 0; mi < 4; ++mi)
#pragma unroll
      for (int ni = 0; ni < 4; ++ni)
        acc[mi][ni] = __builtin_amdgcn_mfma_f32_16x16x32_bf16(af[mi], bf[ni], acc[mi][ni], 0, 0, 0);
  }

  // epilogue: C/D map col = lane&15, row = 4*(lane>>4) + reg  [m89-verified]
#pragma unroll
  for (int mi = 0; mi < 4; ++mi) {
#pragma unroll
    for (int r = 0; r < 4; ++r) {
      const int row = wr * 64 + mi * 16 + g * 4 + r;
      if (row < cnt) {
        const int t = tlist[ts + row];
        float* op = out + (size_t)t * H_DIM + f0 + wc * 64 + l16;
#pragma unroll
        for (int ni = 0; ni < 4; ++ni) op[ni * 16] = acc[mi][ni][r];
      }
    }
  }
}

extern "C" void kernel_launch(void* const* d_in, const int* in_sizes, int n_in,
                              void* d_out, int out_size, void* d_ws, size_t ws_size,
                              hipStream_t stream) {
  const float* x  = (const float*)d_in[0];   // [2,4096,2048]
  const float* wr = (const float*)d_in[1];   // [8,2048]
  const float* we = (const float*)d_in[2];   // [8,2048,2048]
  float* out = (float*)d_out;

  char* p = (char*)d_ws;
  unsigned short* xb = (unsigned short*)p; p += (size_t)T_TOK * H_DIM * 2;  // 32 MB
  int* idx    = (int*)p; p += T_TOK * 4;
  int* tlist  = (int*)p; p += T_TOK * 4;
  int* counts = (int*)p; p += 64;
  int* cursor = (int*)p; p += 64;
  int* te     = (int*)p; p += MAX_TILES * 4;
  int* tstart = (int*)p; p += MAX_TILES * 4;
  int* tcnt   = (int*)p; p += MAX_TILES * 4;
  int* ntl    = (int*)p; p += 64;
  fprintf(stderr, "[moe] ws_size=%zu needed=%zu\n", ws_size, (size_t)(p - (char*)d_ws));

  k_zero<<<1, 64, 0, stream>>>(counts);
  k_router<<<T_TOK / 4, 256, 0, stream>>>(x, wr, xb, idx, counts);
  k_scan<<<1, 1, 0, stream>>>(counts, cursor, te, tstart, tcnt, ntl);
  k_scatter<<<T_TOK / 256, 256, 0, stream>>>(idx, cursor, tlist);
  k_gemm<<<dim3(MAX_TILES, H_DIM / BN), 256, 0, stream>>>(xb, we, tlist, te, tstart, tcnt, ntl, out);
}

// Round 2
// 334.972 us; speedup vs baseline: 1.0721x; 1.0721x over previous
//
#include <hip/hip_runtime.h>
#include <hip/hip_bf16.h>
#include <cstdint>

#define T_TOK 8192
#define H_DIM 2048
#define N_EXP 8
#define BM 128
#define BN 128
#define BK 32
#define MAX_TILES 72
#define LDS_STRIDE 36  // fallback kernel only

typedef __attribute__((ext_vector_type(4))) float f32x4;
typedef __attribute__((ext_vector_type(8))) short bf16x8;

__device__ __forceinline__ unsigned short f2bf(float f) {
  unsigned int u = __builtin_bit_cast(unsigned int, f);
  u += 0x7fffu + ((u >> 16) & 1u);  // RNE (inputs are finite)
  return (unsigned short)(u >> 16);
}

// ---- phase 0: W f32 -> bf16 (once per launch; B-operand becomes LDS-DMA-able) ----
__global__ __launch_bounds__(256) void k_conv_w(const float* __restrict__ we,
                                                unsigned short* __restrict__ wb) {
  const size_t i = ((size_t)blockIdx.x * 256 + threadIdx.x) * 8;
  const f32x4 v0 = *reinterpret_cast<const f32x4*>(we + i);
  const f32x4 v1 = *reinterpret_cast<const f32x4*>(we + i + 4);
  union { unsigned short h[8]; uint4 u; } r;
  r.h[0] = f2bf(v0[0]); r.h[1] = f2bf(v0[1]); r.h[2] = f2bf(v0[2]); r.h[3] = f2bf(v0[3]);
  r.h[4] = f2bf(v1[0]); r.h[5] = f2bf(v1[1]); r.h[6] = f2bf(v1[2]); r.h[7] = f2bf(v1[3]);
  *reinterpret_cast<uint4*>(wb + i) = r.u;
}

// ---- phase 1: router logits + argmax + bf16 cast of x ----
__global__ __launch_bounds__(256) void k_router(const float* __restrict__ x,
    const float* __restrict__ wr, unsigned short* __restrict__ xb,
    int* __restrict__ idx, int* __restrict__ counts)
{
  const int wv = threadIdx.x >> 6, lane = threadIdx.x & 63;
  const int t = blockIdx.x * 4 + wv;
  const float* xp = x + (size_t)t * H_DIM;
  float acc[N_EXP];
#pragma unroll
  for (int e = 0; e < N_EXP; ++e) acc[e] = 0.f;
#pragma unroll
  for (int c = 0; c < H_DIM / 256; ++c) {
    const int h = c * 256 + lane * 4;
    const float4 xv = *reinterpret_cast<const float4*>(xp + h);
    ushort4 bv;
    bv.x = f2bf(xv.x); bv.y = f2bf(xv.y); bv.z = f2bf(xv.z); bv.w = f2bf(xv.w);
    *reinterpret_cast<ushort4*>(xb + (size_t)t * H_DIM + h) = bv;
#pragma unroll
    for (int e = 0; e < N_EXP; ++e) {
      const float4 wv4 = *reinterpret_cast<const float4*>(wr + e * H_DIM + h);
      acc[e] = fmaf(xv.x, wv4.x, acc[e]);
      acc[e] = fmaf(xv.y, wv4.y, acc[e]);
      acc[e] = fmaf(xv.z, wv4.z, acc[e]);
      acc[e] = fmaf(xv.w, wv4.w, acc[e]);
    }
  }
#pragma unroll
  for (int off = 32; off >= 1; off >>= 1)
#pragma unroll
    for (int e = 0; e < N_EXP; ++e) acc[e] += __shfl_xor(acc[e], off, 64);
  float best = acc[0]; int be = 0;
#pragma unroll
  for (int e = 1; e < N_EXP; ++e) if (acc[e] > best) { best = acc[e]; be = e; }
  if (lane == 0) { idx[t] = be; atomicAdd(&counts[be], 1); }
}

// ---- phase 2: one-wave scan + tile map (8 lanes write in parallel) ----
__global__ void k_scan(const int* __restrict__ counts, int* __restrict__ cursor,
                       int* __restrict__ te, int* __restrict__ tstart,
                       int* __restrict__ tcnt, int* __restrict__ ntiles)
{
  const int lane = threadIdx.x;
  const int c = (lane < N_EXP) ? counts[lane] : 0;
  int off = 0, tbase = 0, total_tiles = 0;
#pragma unroll
  for (int j = 0; j < N_EXP; ++j) {
    const int cj = __shfl(c, j, 64);
    const int tj = (cj + BM - 1) / BM;
    if (j < lane) { off += cj; tbase += tj; }
    total_tiles += tj;
  }
  if (lane < N_EXP) {
    cursor[lane] = off;
    const int nt = (c + BM - 1) / BM;
    for (int j = 0; j < nt; ++j) {
      te[tbase + j] = lane;
      tstart[tbase + j] = off + j * BM;
      const int rem = c - j * BM;
      tcnt[tbase + j] = rem < BM ? rem : BM;
    }
    if (lane == 0) *ntiles = total_tiles;
  }
}

__global__ __launch_bounds__(256) void k_scatter(const int* __restrict__ idx,
    int* __restrict__ cursor, int* __restrict__ tlist)
{
  const int t = blockIdx.x * 256 + threadIdx.x;
  const int e = idx[t];
  const int p = atomicAdd(&cursor[e], 1);
  tlist[p] = t;
}

// ---- phase 3 (fast): m97-structure grouped GEMM, bf16 A & B via global_load_lds ----
__global__ __launch_bounds__(256) void k_gemm_bf(const unsigned short* __restrict__ xb,
    const unsigned short* __restrict__ wb, const int* __restrict__ tlist,
    const int* __restrict__ te, const int* __restrict__ tstart,
    const int* __restrict__ tcnt, const int* __restrict__ ntiles,
    float* __restrict__ out)
{
  const int bt = blockIdx.x;
  if (bt >= *ntiles) return;
  const int e = te[bt], ts = tstart[bt], cnt = tcnt[bt];
  const int f0 = blockIdx.y * BN;

  __shared__ short As[BM * BK];   // linear [128][32] shorts (64B rows) — DMA dest
  __shared__ short Bs[BN * BK];

  const int tid = threadIdx.x;
  const int wv = tid >> 6, lane = tid & 63;
  const int wrow = wv >> 1, wcol = wv & 1;   // 2x2 wave grid, 64x64 each
  const int l16 = lane & 15, g = lane >> 4;

  // staging geometry: u = tid + issue*256 covers 512 x 16B; row = u>>2, col = (u&3)*8 shorts
  const int r0 = tid >> 2;
  const int c0 = (tid & 3) * 8;
  const int tokA0 = tlist[ts + (r0 < cnt ? r0 : cnt - 1)];
  const int tokA1 = tlist[ts + (r0 + 64 < cnt ? r0 + 64 : cnt - 1)];
  const unsigned short* ga0 = xb + (size_t)tokA0 * H_DIM + c0;
  const unsigned short* ga1 = xb + (size_t)tokA1 * H_DIM + c0;
  const unsigned short* gb0 = wb + (size_t)e * H_DIM * H_DIM + (size_t)(f0 + r0) * H_DIM + c0;
  const unsigned short* gb1 = gb0 + (size_t)64 * H_DIM;

  // wave-uniform LDS bases (lane*16 added by HW); issue i covers bytes (wv*64 + i*256)*16
  auto* lA0 = (__attribute__((address_space(3))) char*)As + (wv * 64) * 16;
  auto* lA1 = (__attribute__((address_space(3))) char*)As + (wv * 64 + 256) * 16;
  auto* lB0 = (__attribute__((address_space(3))) char*)Bs + (wv * 64) * 16;
  auto* lB1 = (__attribute__((address_space(3))) char*)Bs + (wv * 64 + 256) * 16;

  f32x4 acc[4][4];
#pragma unroll
  for (int mi = 0; mi < 4; ++mi)
#pragma unroll
    for (int ni = 0; ni < 4; ++ni) acc[mi][ni] = (f32x4){0.f, 0.f, 0.f, 0.f};

  for (int k0 = 0; k0 < H_DIM; k0 += BK) {
    __syncthreads();  // previous iter's ds_reads done before overwrite
    __builtin_amdgcn_global_load_lds((const __attribute__((address_space(1))) void*)(ga0 + k0),
                                     (__attribute__((address_space(3))) void*)lA0, 16, 0, 0);
    __builtin_amdgcn_global_load_lds((const __attribute__((address_space(1))) void*)(ga1 + k0),
                                     (__attribute__((address_space(3))) void*)lA1, 16, 0, 0);
    __builtin_amdgcn_global_load_lds((const __attribute__((address_space(1))) void*)(gb0 + k0),
                                     (__attribute__((address_space(3))) void*)lB0, 16, 0, 0);
    __builtin_amdgcn_global_load_lds((const __attribute__((address_space(1))) void*)(gb1 + k0),
                                     (__attribute__((address_space(3))) void*)lB1, 16, 0, 0);
    __syncthreads();  // compiler drains vmcnt(0) before barrier

    bf16x8 af[4], bfm[4];
#pragma unroll
    for (int mi = 0; mi < 4; ++mi)
      af[mi] = *reinterpret_cast<const bf16x8*>(&As[(wrow * 64 + mi * 16 + l16) * BK + g * 8]);
#pragma unroll
    for (int ni = 0; ni < 4; ++ni)
      bfm[ni] = *reinterpret_cast<const bf16x8*>(&Bs[(wcol * 64 + ni * 16 + l16) * BK + g * 8]);
#pragma unroll
    for (int mi = 0; mi < 4; ++mi)
#pragma unroll
      for (int ni = 0; ni < 4; ++ni)
        acc[mi][ni] = __builtin_amdgcn_mfma_f32_16x16x32_bf16(af[mi], bfm[ni], acc[mi][ni], 0, 0, 0);
  }

  // epilogue: C/D map col = lane&15, row = 4*(lane>>4) + reg  [m89-verified]
#pragma unroll
  for (int mi = 0; mi < 4; ++mi) {
#pragma unroll
    for (int r = 0; r < 4; ++r) {
      const int row = wrow * 64 + mi * 16 + g * 4 + r;
      if (row < cnt) {
        const int t = tlist[ts + row];
        float* op = out + (size_t)t * H_DIM + f0 + wcol * 64 + l16;
#pragma unroll
        for (int ni = 0; ni < 4; ++ni) op[ni * 16] = acc[mi][ni][r];
      }
    }
  }
}

// ---- phase 3 (fallback if ws too small): round-1 GEMM, f32 B reg-staging ----
__global__ __launch_bounds__(256) void k_gemm_f32(const unsigned short* __restrict__ xb,
    const float* __restrict__ we, const int* __restrict__ tlist,
    const int* __restrict__ te, const int* __restrict__ tstart,
    const int* __restrict__ tcnt, const int* __restrict__ ntiles,
    float* __restrict__ out)
{
  const int bt = blockIdx.x;
  if (bt >= *ntiles) return;
  const int e = te[bt], ts = tstart[bt], cnt = tcnt[bt];
  const int f0 = blockIdx.y * BN;

  __shared__ short As[BM][LDS_STRIDE];
  __shared__ short Bs[BN][LDS_STRIDE];

  const int tid = threadIdx.x;
  const int wv = tid >> 6, lane = tid & 63;
  const int wrow = wv >> 1, wcol = wv & 1;
  const int l16 = lane & 15, g = lane >> 4;

  int tok[4];
#pragma unroll
  for (int i = 0; i < 4; ++i) {
    const int row = (tid + i * 256) >> 3;
    tok[i] = tlist[ts + (row < cnt ? row : cnt - 1)];
  }
  const float* wbp = we + (size_t)e * H_DIM * H_DIM;

  f32x4 acc[4][4];
#pragma unroll
  for (int mi = 0; mi < 4; ++mi)
#pragma unroll
    for (int ni = 0; ni < 4; ++ni) acc[mi][ni] = (f32x4){0.f, 0.f, 0.f, 0.f};

  union Frag { short4 h[2]; bf16x8 v; };

  for (int k0 = 0; k0 < H_DIM; k0 += BK) {
    __syncthreads();
#pragma unroll
    for (int i = 0; i < 4; ++i) {
      const int u = tid + i * 256;
      const int row = u >> 3, c4 = (u & 7) * 4;
      *reinterpret_cast<short4*>(&As[row][c4]) =
          *reinterpret_cast<const short4*>(xb + (size_t)tok[i] * H_DIM + k0 + c4);
      const f32x4 wv4 = *reinterpret_cast<const f32x4*>(
          wbp + (size_t)(f0 + row) * H_DIM + k0 + c4);
      short4 bv;
      bv.x = (short)f2bf(wv4[0]); bv.y = (short)f2bf(wv4[1]);
      bv.z = (short)f2bf(wv4[2]); bv.w = (short)f2bf(wv4[3]);
      *reinterpret_cast<short4*>(&Bs[row][c4]) = bv;
    }
    __syncthreads();

    bf16x8 af[4], bfm[4];
#pragma unroll
    for (int mi = 0; mi < 4; ++mi) {
      Frag fr;
      const short* p = &As[wrow * 64 + mi * 16 + l16][g * 4];
      fr.h[0] = *reinterpret_cast<const short4*>(p);
      fr.h[1] = *reinterpret_cast<const short4*>(p + 16);
      af[mi] = fr.v;
    }
#pragma unroll
    for (int ni = 0; ni < 4; ++ni) {
      Frag fr;
      const short* p = &Bs[wcol * 64 + ni * 16 + l16][g * 4];
      fr.h[0] = *reinterpret_cast<const short4*>(p);
      fr.h[1] = *reinterpret_cast<const short4*>(p + 16);
      bfm[ni] = fr.v;
    }
#pragma unroll
    for (int mi = 0; mi < 4; ++mi)
#pragma unroll
      for (int ni = 0; ni < 4; ++ni)
        acc[mi][ni] = __builtin_amdgcn_mfma_f32_16x16x32_bf16(af[mi], bfm[ni], acc[mi][ni], 0, 0, 0);
  }

#pragma unroll
  for (int mi = 0; mi < 4; ++mi) {
#pragma unroll
    for (int r = 0; r < 4; ++r) {
      const int row = wrow * 64 + mi * 16 + g * 4 + r;
      if (row < cnt) {
        const int t = tlist[ts + row];
        float* op = out + (size_t)t * H_DIM + f0 + wcol * 64 + l16;
#pragma unroll
        for (int ni = 0; ni < 4; ++ni) op[ni * 16] = acc[mi][ni][r];
      }
    }
  }
}

extern "C" void kernel_launch(void* const* d_in, const int* in_sizes, int n_in,
                              void* d_out, int out_size, void* d_ws, size_t ws_size,
                              hipStream_t stream) {
  const float* x  = (const float*)d_in[0];   // [2,4096,2048]
  const float* wr = (const float*)d_in[1];   // [8,2048]
  const float* we = (const float*)d_in[2];   // [8,2048,2048]
  float* out = (float*)d_out;

  char* p = (char*)d_ws;
  unsigned short* xb = (unsigned short*)p; p += (size_t)T_TOK * H_DIM * 2;  // 32 MB
  int* idx    = (int*)p; p += T_TOK * 4;
  int* tlist  = (int*)p; p += T_TOK * 4;
  int* counts = (int*)p; p += 64;
  int* cursor = (int*)p; p += 64;
  int* te     = (int*)p; p += MAX_TILES * 4;
  int* tstart = (int*)p; p += MAX_TILES * 4;
  int* tcnt   = (int*)p; p += MAX_TILES * 4;
  int* ntl    = (int*)p; p += 64;
  size_t off = (size_t)(p - (char*)d_ws);
  off = (off + 255) & ~(size_t)255;
  unsigned short* wb = (unsigned short*)((char*)d_ws + off);      // 64 MB bf16 W
  const size_t need = off + (size_t)N_EXP * H_DIM * H_DIM * 2;
  const bool fast = ws_size >= need;

  hipMemsetAsync(counts, 0, 64, stream);
  if (fast) k_conv_w<<<(N_EXP * H_DIM * H_DIM) / (256 * 8), 256, 0, stream>>>(we, wb);
  k_router<<<T_TOK / 4, 256, 0, stream>>>(x, wr, xb, idx, counts);
  k_scan<<<1, 64, 0, stream>>>(counts, cursor, te, tstart, tcnt, ntl);
  k_scatter<<<T_TOK / 256, 256, 0, stream>>>(idx, cursor, tlist);
  if (fast)
    k_gemm_bf<<<dim3(MAX_TILES, H_DIM / BN), 256, 0, stream>>>(xb, wb, tlist, te, tstart, tcnt, ntl, out);
  else
    k_gemm_f32<<<dim3(MAX_TILES, H_DIM / BN), 256, 0, stream>>>(xb, we, tlist, te, tstart, tcnt, ntl, out);
}

// Round 3
// 293.821 us; speedup vs baseline: 1.2223x; 1.1401x over previous
//
#include <hip/hip_runtime.h>
#include <hip/hip_bf16.h>
#include <cstdint>

#define T_TOK 8192
#define H_DIM 2048
#define N_EXP 8
// GEMM: BM=BN=256, BK=64, 8 waves (512 thr), per-wave 128x64 (template geometry)

typedef __attribute__((ext_vector_type(4))) float f32x4;
typedef __attribute__((ext_vector_type(8))) short bf16x8;

__device__ __forceinline__ unsigned short f2bf(float f) {
  unsigned int u = __builtin_bit_cast(unsigned int, f);
  u += 0x7fffu + ((u >> 16) & 1u);  // RNE
  return (unsigned short)(u >> 16);
}

// ---- phase 0: W f32 -> bf16 ----
__global__ __launch_bounds__(256) void k_conv_w(const float* __restrict__ we,
                                                unsigned short* __restrict__ wb) {
  const size_t i = ((size_t)blockIdx.x * 256 + threadIdx.x) * 8;
  const f32x4 v0 = *reinterpret_cast<const f32x4*>(we + i);
  const f32x4 v1 = *reinterpret_cast<const f32x4*>(we + i + 4);
  union { unsigned short h[8]; uint4 u; } r;
  r.h[0] = f2bf(v0[0]); r.h[1] = f2bf(v0[1]); r.h[2] = f2bf(v0[2]); r.h[3] = f2bf(v0[3]);
  r.h[4] = f2bf(v1[0]); r.h[5] = f2bf(v1[1]); r.h[6] = f2bf(v1[2]); r.h[7] = f2bf(v1[3]);
  *reinterpret_cast<uint4*>(wb + i) = r.u;
}

// ---- phase 1: router logits + argmax + bf16 cast of x ----
__global__ __launch_bounds__(256) void k_router(const float* __restrict__ x,
    const float* __restrict__ wr, unsigned short* __restrict__ xb,
    int* __restrict__ idx, int* __restrict__ counts)
{
  const int wv = threadIdx.x >> 6, lane = threadIdx.x & 63;
  const int t = blockIdx.x * 4 + wv;
  const float* xp = x + (size_t)t * H_DIM;
  float acc[N_EXP];
#pragma unroll
  for (int e = 0; e < N_EXP; ++e) acc[e] = 0.f;
#pragma unroll
  for (int c = 0; c < H_DIM / 256; ++c) {
    const int h = c * 256 + lane * 4;
    const float4 xv = *reinterpret_cast<const float4*>(xp + h);
    ushort4 bv;
    bv.x = f2bf(xv.x); bv.y = f2bf(xv.y); bv.z = f2bf(xv.z); bv.w = f2bf(xv.w);
    *reinterpret_cast<ushort4*>(xb + (size_t)t * H_DIM + h) = bv;
#pragma unroll
    for (int e = 0; e < N_EXP; ++e) {
      const float4 wv4 = *reinterpret_cast<const float4*>(wr + e * H_DIM + h);
      acc[e] = fmaf(xv.x, wv4.x, acc[e]);
      acc[e] = fmaf(xv.y, wv4.y, acc[e]);
      acc[e] = fmaf(xv.z, wv4.z, acc[e]);
      acc[e] = fmaf(xv.w, wv4.w, acc[e]);
    }
  }
#pragma unroll
  for (int off = 32; off >= 1; off >>= 1)
#pragma unroll
    for (int e = 0; e < N_EXP; ++e) acc[e] += __shfl_xor(acc[e], off, 64);
  float best = acc[0]; int be = 0;
#pragma unroll
  for (int e = 1; e < N_EXP; ++e) if (acc[e] > best) { best = acc[e]; be = e; }
  if (lane == 0) { idx[t] = be; atomicAdd(&counts[be], 1); }
}

// ---- phase 2: scan + per-256-row-tile segment map (one wave) ----
__global__ void k_scan(const int* __restrict__ counts, int* __restrict__ cursor,
                       int* __restrict__ nseg, int* __restrict__ sege,
                       int* __restrict__ seglo, int* __restrict__ seghi)
{
  const int lane = threadIdx.x;
  int off[N_EXP + 1]; off[0] = 0;
#pragma unroll
  for (int e = 0; e < N_EXP; ++e) off[e + 1] = off[e] + counts[e];
  if (lane < N_EXP) cursor[lane] = off[lane];
  if (lane < 32) {
    const int lo = lane * 256, hi = lo + 256;
    int n = 0;
#pragma unroll
    for (int e = 0; e < N_EXP; ++e) {
      const int a = off[e] > lo ? off[e] : lo;
      const int b = off[e + 1] < hi ? off[e + 1] : hi;
      if (a < b) { sege[lane * 8 + n] = e; seglo[lane * 8 + n] = a - lo; seghi[lane * 8 + n] = b - lo; ++n; }
    }
    nseg[lane] = n;
  }
}

__global__ __launch_bounds__(256) void k_scatter(const int* __restrict__ idx,
    int* __restrict__ cursor, int* __restrict__ tlist)
{
  const int t = blockIdx.x * 256 + threadIdx.x;
  const int e = idx[t];
  const int p = atomicAdd(&cursor[e], 1);
  tlist[p] = t;
}

// ---- phase 3: grouped GEMM, 256x256 tile, BK=64, 2-ks-phase counted-vmcnt pipeline ----
// LDS layout per buffer (64KB): A[2 ks][256 row][32 col bf16], then B same. 2 buffers = 128KB.
// Swizzle: 16B-chunk index within 64B row ^= (row>>1)&3  (8-slot spread -> 2 lanes/slot, free).
// Staged via global_load_lds (linear dest) from pre-swizzled global source (rule #21).
#define GLL(SRC, OFF) __builtin_amdgcn_global_load_lds( \
    (const __attribute__((address_space(1))) void*)(SRC), \
    (__attribute__((address_space(3))) void*)(LDS3 + (OFF)), 16, 0, 0)

__global__ __launch_bounds__(512, 2) void k_gemm(const unsigned short* __restrict__ xb,
    const unsigned short* __restrict__ wb, const int* __restrict__ tlist,
    const int* __restrict__ nseg, const int* __restrict__ sege,
    const int* __restrict__ seglo, const int* __restrict__ seghi,
    float* __restrict__ out)
{
  __shared__ short lds[65536];  // 128 KiB
  const int mt = blockIdx.x >> 3, nt = blockIdx.x & 7;  // &7: N-tile -> XCD (L2 W-panel locality)
  const int m0 = mt * 256, f0 = nt * 256;
  const int tid = threadIdx.x;
  const int l = tid & 63, wv = tid >> 6;
  const int wm = wv >> 2, wn = wv & 3;            // 2M x 4N waves, 128x64 each
  const int l16 = l & 15, g = l >> 4;
  const int cSwz = (g * 16) ^ (((l16 >> 1) & 3) << 4);
  const char* LP = (const char*)lds;
  auto* LDS3 = (__attribute__((address_space(3))) char*)lds;

  // staging geometry: per wave-issue 64 lanes x 16B = 16 rows x 64B
  const int srow = wv * 16 + (l >> 2);            // row within 128-row half
  const int scol = (((l & 3) * 16) ^ (((srow >> 1) & 3) << 4)) >> 1;  // pre-swizzled elem col
  const int tokA0 = tlist[m0 + srow];
  const int tokA1 = tlist[m0 + 128 + srow];
  const unsigned short* aS0 = xb + (size_t)tokA0 * H_DIM + scol;
  const unsigned short* aS1 = xb + (size_t)tokA1 * H_DIM + scol;

  const unsigned short* bS0 = wb;
  const unsigned short* bS1 = wb;
  unsigned mmask = 0;
  f32x4 acc[8][4];

  auto stage = [&](int grp, int kn, int nb) {   // grp = ks half (0/1), 4 gload_lds
    GLL(aS0 + kn + grp * 32, nb * 65536 + grp * 16384 + wv * 1024);
    GLL(aS1 + kn + grp * 32, nb * 65536 + grp * 16384 + 8192 + wv * 1024);
    GLL(bS0 + kn + grp * 32, nb * 65536 + 32768 + grp * 16384 + wv * 1024);
    GLL(bS1 + kn + grp * 32, nb * 65536 + 32768 + grp * 16384 + 8192 + wv * 1024);
  };

  // Pipeline invariant (per wave, 4 gloads per group):
  //  P0(kt): reads g0(kt); issues g0(kt+1); vmcnt(4) completes g1(kt)   [needed by P1]
  //  P1(kt): reads g1(kt); issues g1(kt+1); vmcnt(4) completes g0(kt+1) [needed by next P0]
  // Never drains to 0 mid-loop; cross-wave visibility via own-vmcnt-then-barrier.
  auto phase = [&](int buf, int ks, int kn, int nb, int mode) {  // mode 0=stage+v4, 1=v0, 2=none
    bf16x8 afr[8], bfr[4];
#pragma unroll
    for (int nf = 0; nf < 4; ++nf)
      bfr[nf] = *reinterpret_cast<const bf16x8*>(
          LP + buf * 65536 + 32768 + ks * 16384 + (wn * 64 + nf * 16 + l16) * 64 + cSwz);
#pragma unroll
    for (int mf = 0; mf < 8; ++mf)
      if (mmask & (1u << mf))
        afr[mf] = *reinterpret_cast<const bf16x8*>(
            LP + buf * 65536 + ks * 16384 + (wm * 128 + mf * 16 + l16) * 64 + cSwz);
    if (mode == 0) {
      stage(ks, kn, nb);
      asm volatile("s_waitcnt vmcnt(4)" ::: "memory");
    } else if (mode == 1) {
      asm volatile("s_waitcnt vmcnt(0)" ::: "memory");
    }
    __builtin_amdgcn_s_barrier();
    __builtin_amdgcn_sched_barrier(0);
    __builtin_amdgcn_s_setprio(1);
#pragma unroll
    for (int mf = 0; mf < 8; ++mf)
      if (mmask & (1u << mf)) {
#pragma unroll
        for (int nf = 0; nf < 4; ++nf)
          acc[mf][nf] = __builtin_amdgcn_mfma_f32_16x16x32_bf16(afr[mf], bfr[nf], acc[mf][nf], 0, 0, 0);
      }
    __builtin_amdgcn_sched_barrier(0);
    __builtin_amdgcn_s_setprio(0);
    asm volatile("" ::: "memory");
    __builtin_amdgcn_s_barrier();
    __builtin_amdgcn_sched_barrier(0);
  };

  const int ns = nseg[mt];
  for (int s = 0; s < ns; ++s) {
    const int eS = sege[mt * 8 + s];
    const int rlo = seglo[mt * 8 + s], rhi = seghi[mt * 8 + s];
    mmask = 0;
#pragma unroll
    for (int mf = 0; mf < 8; ++mf) {
      const int fr = wm * 128 + mf * 16;
      if (fr < rhi && fr + 16 > rlo) mmask |= 1u << mf;
    }
    bS0 = wb + (size_t)eS * H_DIM * H_DIM + (size_t)(f0 + srow) * H_DIM + scol;
    bS1 = bS0 + (size_t)128 * H_DIM;
#pragma unroll
    for (int mf = 0; mf < 8; ++mf)
#pragma unroll
      for (int nf = 0; nf < 4; ++nf) acc[mf][nf] = (f32x4){0.f, 0.f, 0.f, 0.f};

    // prologue: stage K-tile 0 into buf 0; wait first half-group only
    stage(0, 0, 0); stage(1, 0, 0);
    asm volatile("s_waitcnt vmcnt(4)" ::: "memory");
    __builtin_amdgcn_s_barrier();
    __builtin_amdgcn_sched_barrier(0);

    for (int kt = 0; kt < 32; ++kt) {
      const int cur = kt & 1, nxt = cur ^ 1;
      const int kn = (kt + 1) * 64;
      const bool last = (kt == 31);
      phase(cur, 0, kn, nxt, last ? 1 : 0);
      phase(cur, 1, kn, nxt, last ? 2 : 0);
    }

    // epilogue: C/D map col=lane&15, row=4*(lane>>4)+reg [m89]; per-row segment guard
#pragma unroll
    for (int mf = 0; mf < 8; ++mf) {
#pragma unroll
      for (int r = 0; r < 4; ++r) {
        const int row = wm * 128 + mf * 16 + g * 4 + r;
        if (row >= rlo && row < rhi) {
          const int t = tlist[m0 + row];
          float* op = out + (size_t)t * H_DIM + f0 + wn * 64 + l16;
#pragma unroll
          for (int nf = 0; nf < 4; ++nf) op[nf * 16] = acc[mf][nf][r];
        }
      }
    }
  }
}

extern "C" void kernel_launch(void* const* d_in, const int* in_sizes, int n_in,
                              void* d_out, int out_size, void* d_ws, size_t ws_size,
                              hipStream_t stream) {
  const float* x  = (const float*)d_in[0];   // [2,4096,2048]
  const float* wr = (const float*)d_in[1];   // [8,2048]
  const float* we = (const float*)d_in[2];   // [8,2048,2048]
  float* out = (float*)d_out;

  char* p = (char*)d_ws;
  unsigned short* xb = (unsigned short*)p; p += (size_t)T_TOK * H_DIM * 2;  // 32 MB
  int* idx    = (int*)p; p += T_TOK * 4;
  int* tlist  = (int*)p; p += T_TOK * 4;
  int* counts = (int*)p; p += 64;
  int* cursor = (int*)p; p += 64;
  int* nsegp  = (int*)p; p += 32 * 4;
  int* sege   = (int*)p; p += 256 * 4;
  int* seglo  = (int*)p; p += 256 * 4;
  int* seghi  = (int*)p; p += 256 * 4;
  size_t off = (size_t)(p - (char*)d_ws);
  off = (off + 255) & ~(size_t)255;
  unsigned short* wb = (unsigned short*)((char*)d_ws + off);  // 64 MB bf16 W

  hipMemsetAsync(counts, 0, 64, stream);
  k_conv_w<<<(N_EXP * H_DIM * H_DIM) / (256 * 8), 256, 0, stream>>>(we, wb);
  k_router<<<T_TOK / 4, 256, 0, stream>>>(x, wr, xb, idx, counts);
  k_scan<<<1, 64, 0, stream>>>(counts, cursor, nsegp, sege, seglo, seghi);
  k_scatter<<<T_TOK / 256, 256, 0, stream>>>(idx, cursor, tlist);
  k_gemm<<<256, 512, 0, stream>>>(xb, wb, tlist, nsegp, sege, seglo, seghi, out);
}